// Round 3
// baseline (266.709 us; speedup 1.0000x reference)
//
#include <hip/hip_runtime.h>
#include <cmath>

#define B_SZ 512
#define D_SZ 128
#define K_SZ 4096
#define NDATA 500000
#define TEMP 0.07f
#define MOM 0.5f
#define EPSN 1e-12f
#define SPLIT 4

typedef float f32x4 __attribute__((ext_vector_type(4)));

// ---------------- kernel A: normalize s,t + pos logits ----------------
__global__ void knorm(const float* __restrict__ s_in, const float* __restrict__ t_in,
                      float* __restrict__ s_n, float* __restrict__ t_n,
                      float* __restrict__ pos) {
    int b = blockIdx.x;
    int l = threadIdx.x;  // 64 lanes, each handles 2 floats
    float2 sv = ((const float2*)(s_in + b * D_SZ))[l];
    float2 tv = ((const float2*)(t_in + b * D_SZ))[l];
    float ss = sv.x * sv.x + sv.y * sv.y;
    float tt = tv.x * tv.x + tv.y * tv.y;
    for (int m = 1; m < 64; m <<= 1) {
        ss += __shfl_xor(ss, m, 64);
        tt += __shfl_xor(tt, m, 64);
    }
    float sinv = 1.0f / fmaxf(sqrtf(ss), EPSN);
    float tinv = 1.0f / fmaxf(sqrtf(tt), EPSN);
    float2 sn = {sv.x * sinv, sv.y * sinv};
    float2 tn = {tv.x * tinv, tv.y * tinv};
    ((float2*)(s_n + b * D_SZ))[l] = sn;
    ((float2*)(t_n + b * D_SZ))[l] = tn;
    float d = sn.x * tn.x + sn.y * tn.y;
    for (int m = 1; m < 64; m <<= 1) d += __shfl_xor(d, m, 64);
    if (l == 0) pos[b] = d * (1.0f / TEMP);
}

// ---------------- kernel B: copy bank -> out (out offset by 1 float) ----------------
__global__ void kcopy(const float* __restrict__ src, float* __restrict__ dst /* = d_out+1 */) {
    const long long total = (long long)NDATA * D_SZ;  // 64,000,000
    long long tid = blockIdx.x * (long long)blockDim.x + threadIdx.x;
    long long nthr = gridDim.x * (long long)blockDim.x;
    if (tid == 0) {
        dst[0] = src[0];
        dst[1] = src[1];
        dst[2] = src[2];
        dst[total - 1] = src[total - 1];
    }
    // float4-aligned region of dst starts at dst+3 (d_out+4 -> 16B aligned)
    const long long NV = (total - 4) / 4;  // 15,999,999 vectors
    float* dst4 = dst + 3;
    const float* srcb = src + 3;
    for (long long i = tid; i < NV; i += nthr) {
        f32x4 v;
        v.x = srcb[4 * i + 0];
        v.y = srcb[4 * i + 1];
        v.z = srcb[4 * i + 2];
        v.w = srcb[4 * i + 3];
        __builtin_nontemporal_store(v, (f32x4*)dst4 + i);
    }
}

// ---------------- kernel C: momentum scatter-update (last-wins) ----------------
__global__ void kupdate(const int* __restrict__ indices, const float* __restrict__ bank,
                        const float* __restrict__ t_n, float* __restrict__ outBank /* d_out+1 */) {
    int j = blockIdx.x;
    int l = threadIdx.x;  // 64
    int idx = indices[j];
    // numpy fancy-assignment semantics: last occurrence wins
    for (int j2 = j + 1; j2 < B_SZ; ++j2)
        if (indices[j2] == idx) return;
    float2 bv = ((const float2*)(bank + (long long)idx * D_SZ))[l];
    float2 tv = ((const float2*)(t_n + j * D_SZ))[l];
    float2 u = {MOM * bv.x + (1.0f - MOM) * tv.x, MOM * bv.y + (1.0f - MOM) * tv.y};
    float ss = u.x * u.x + u.y * u.y;
    for (int m = 1; m < 64; m <<= 1) ss += __shfl_xor(ss, m, 64);
    float inv = 1.0f / fmaxf(sqrtf(ss), EPSN);
    float* dst = outBank + (long long)idx * D_SZ + l * 2;  // 4B-aligned only
    dst[0] = u.x * inv;
    dst[1] = u.y * inv;
}

// ---------------- kernel D: gather negatives, dot, online LSE partials ----------------
__global__ __launch_bounds__(256) void kneg(const float* __restrict__ bank,
                                            const int* __restrict__ negidx,
                                            const float* __restrict__ s_n,
                                            float2* __restrict__ partials) {
    const int split = blockIdx.x;
    const int b = blockIdx.y;
    __shared__ float s_lds[D_SZ];
    int tid = threadIdx.x;
    if (tid < 32) ((float4*)s_lds)[tid] = ((const float4*)(s_n + b * D_SZ))[tid];
    __syncthreads();
    const int lane = tid & 31;
    const int grp = tid >> 5;  // 8 groups of 32 lanes
    float4 sv = ((const float4*)s_lds)[lane];
    float m = -INFINITY, ssum = 0.0f;
    const int base = b * K_SZ + split * (K_SZ / SPLIT);
    const int iters = (K_SZ / SPLIT) / 8;  // 128
    for (int it = 0; it < iters; ++it) {
        int k = it * 8 + grp;
        int idx = negidx[base + k];
        float4 v = ((const float4*)(bank + (long long)idx * D_SZ))[lane];
        float d = v.x * sv.x + v.y * sv.y + v.z * sv.z + v.w * sv.w;
        d += __shfl_xor(d, 1, 32);
        d += __shfl_xor(d, 2, 32);
        d += __shfl_xor(d, 4, 32);
        d += __shfl_xor(d, 8, 32);
        d += __shfl_xor(d, 16, 32);
        d *= (1.0f / TEMP);
        float mn = fmaxf(m, d);
        ssum = ssum * __expf(m - mn) + __expf(d - mn);
        m = mn;
    }
    __shared__ float2 gp[8];
    if (lane == 0) gp[grp] = make_float2(m, ssum);
    __syncthreads();
    if (tid == 0) {
        float M = gp[0].x, S = gp[0].y;
        for (int g = 1; g < 8; ++g) {
            float mg = gp[g].x, sg = gp[g].y;
            float mn = fmaxf(M, mg);
            S = S * __expf(M - mn) + sg * __expf(mg - mn);
            M = mn;
        }
        partials[b * SPLIT + split] = make_float2(M, S);
    }
}

// ---------------- kernel E: combine partials -> loss ----------------
__global__ void kfinal(const float2* __restrict__ partials, const float* __restrict__ pos,
                       float* __restrict__ out) {
    __shared__ float red[B_SZ];
    int t = threadIdx.x;  // 512 threads, one per batch row
    float M = -INFINITY, S = 0.0f;
    for (int p = 0; p < SPLIT; ++p) {
        float2 ms = partials[t * SPLIT + p];
        float mn = fmaxf(M, ms.x);
        S = S * __expf(M - mn) + ms.y * __expf(ms.x - mn);
        M = mn;
    }
    float pl = pos[t];
    float mn = fmaxf(M, pl);
    S = S * __expf(M - mn) + __expf(pl - mn);
    M = mn;
    float lse = M + logf(S);
    red[t] = lse - pl;
    __syncthreads();
    for (int off = 256; off > 0; off >>= 1) {
        if (t < off) red[t] += red[t + off];
        __syncthreads();
    }
    if (t == 0) out[0] = red[0] * (1.0f / (float)B_SZ);
}

extern "C" void kernel_launch(void* const* d_in, const int* in_sizes, int n_in,
                              void* d_out, int out_size, void* d_ws, size_t ws_size,
                              hipStream_t stream) {
    const float* student = (const float*)d_in[0];
    const float* teacher = (const float*)d_in[1];
    const float* bank    = (const float*)d_in[2];
    const int*   indices = (const int*)d_in[3];
    const int*   negidx  = (const int*)d_in[4];
    float* out = (float*)d_out;

    // workspace layout (floats)
    float* ws = (float*)d_ws;
    float* s_n      = ws;                       // 512*128
    float* t_n      = s_n + B_SZ * D_SZ;        // 512*128
    float* pos      = t_n + B_SZ * D_SZ;        // 512
    float2* partials = (float2*)(pos + B_SZ);   // 512*SPLIT float2

    // 1) normalize + pos logits
    knorm<<<B_SZ, 64, 0, stream>>>(student, teacher, s_n, t_n, pos);
    // 2) copy bank into output (offset 1)
    kcopy<<<4096, 256, 0, stream>>>(bank, out + 1);
    // 3) momentum scatter-update of indexed rows (after copy)
    kupdate<<<B_SZ, 64, 0, stream>>>(indices, bank, t_n, out + 1);
    // 4) negative logits + per-split online LSE
    dim3 g(SPLIT, B_SZ);
    kneg<<<g, 256, 0, stream>>>(bank, negidx, s_n, partials);
    // 5) final loss
    kfinal<<<1, B_SZ, 0, stream>>>(partials, pos, out);
}